// Round 1
// baseline (195.915 us; speedup 1.0000x reference)
//
#include <hip/hip_runtime.h>

#define NH 16
#define DKV 64

typedef __bf16 bf16x8 __attribute__((ext_vector_type(8)));
typedef unsigned short u16x8 __attribute__((ext_vector_type(8)));
typedef float f32x4 __attribute__((ext_vector_type(4)));
typedef unsigned short u16;

__device__ __forceinline__ u16 f2bu(float f) {
    unsigned int u = __builtin_bit_cast(unsigned int, f);
    u = (u + 0x7FFFu + ((u >> 16) & 1u)) >> 16;
    return (u16)u;
}
__device__ __forceinline__ bf16x8 ld_bf8(const u16* p) {
    return __builtin_bit_cast(bf16x8, *(const u16x8*)p);
}

// ---------------- prep kernels ----------------
__global__ void prep_cast(const float* __restrict__ x, u16* __restrict__ xb, int n) {
    int i = (blockIdx.x * 256 + threadIdx.x) * 4;
    if (i >= n) return;
    float4 v = *(const float4*)&x[i];
    u16 o0 = f2bu(v.x), o1 = f2bu(v.y), o2 = f2bu(v.z), o3 = f2bu(v.w);
    xb[i] = o0; xb[i+1] = o1; xb[i+2] = o2; xb[i+3] = o3;
}

// src f32 [1024][1024] -> dst bf16 [1024][1024] transposed (dst[n][k] = src[k][n])
__global__ void prep_transpose(const float* __restrict__ src, u16* __restrict__ dst) {
    __shared__ float tile[32][33];
    int r0 = blockIdx.y * 32, c0 = blockIdx.x * 32;
    int tx = threadIdx.x, ty = threadIdx.y;
    #pragma unroll
    for (int i = 0; i < 32; i += 8)
        tile[ty + i][tx] = src[(size_t)(r0 + ty + i) * 1024 + c0 + tx];
    __syncthreads();
    #pragma unroll
    for (int i = 0; i < 32; i += 8)
        dst[(size_t)(c0 + ty + i) * 1024 + r0 + tx] = f2bu(tile[tx][ty + i]);
}

__device__ __forceinline__ int rel_bucket(int delta) {
    // exact integer version of the reference fp32 bucket formula (bidirectional,
    // num_buckets=32, max_distance=128); thresholds derived analytically.
    int n = -delta;
    int ret = (n < 0) ? 16 : 0;
    int na = n < 0 ? -n : n;
    int b;
    if (na < 8) b = na;
    else if (na < 12) b = 8;
    else if (na < 16) b = 9;
    else if (na < 23) b = 10;
    else if (na < 32) b = 11;
    else if (na < 46) b = 12;
    else if (na < 64) b = 13;
    else if (na < 91) b = 14;
    else b = 15;
    return b + ret;
}

__global__ void prep_bias(const float* __restrict__ tbl, float* __restrict__ biasT, int T) {
    int idx = blockIdx.x * 256 + threadIdx.x;
    int W = 2 * T - 1;
    if (idx >= NH * W) return;
    int d = idx % W - (T - 1);           // delta = pos_k - pos_q
    int h = idx / W;
    biasT[idx] = tbl[rel_bucket(d) * NH + h];
}

__global__ void prep_meta(const int* __restrict__ q_lens, int nseq, int T,
                          int* __restrict__ seqid, int* __restrict__ kvs, int* __restrict__ kve) {
    int t = blockIdx.x * 256 + threadIdx.x;
    if (t >= T) return;
    int start = 0, sid = -1, a = 0, b = 0;
    for (int i = 0; i < nseq; ++i) {
        int len = q_lens[i];
        if (t >= start && t < start + len) { sid = i; a = start; b = start + len; }
        start += len;
    }
    seqid[t] = sid; kvs[t] = a; kve[t] = b;
}

// ---------------- GEMM (A [M][K] bf16 row-major, Bt [N][K] bf16 row-major) ----------------
// MODE 0: C f32 [M][N].  MODE 1: qkv epilogue (cols<2048 -> qkb bf16, cols>=2048 -> vtb transposed)
template<int MODE>
__global__ __launch_bounds__(256)
void gemm_bt(const u16* __restrict__ A, const u16* __restrict__ Bt,
             int M, int N, int K, int T,
             float* __restrict__ Cf, u16* __restrict__ qkb, u16* __restrict__ vtb) {
    __shared__ __attribute__((aligned(16))) u16 As[128][72];
    __shared__ __attribute__((aligned(16))) u16 Bs[128][72];
    const int tid = threadIdx.x;
    const int l = tid & 63, wv = tid >> 6;
    const int l16 = l & 15, lg = l >> 4;
    const int wm = (wv >> 1) * 64, wn = (wv & 1) * 64;
    const int bm = blockIdx.x * 128, bn = blockIdx.y * 128;
    f32x4 acc[4][4];
    #pragma unroll
    for (int i = 0; i < 4; i++)
        #pragma unroll
        for (int j = 0; j < 4; j++)
            #pragma unroll
            for (int r = 0; r < 4; r++) acc[i][j][r] = 0.f;

    for (int k0 = 0; k0 < K; k0 += 64) {
        __syncthreads();
        #pragma unroll
        for (int c = 0; c < 4; ++c) {
            int chunk = c * 256 + tid;
            int row = chunk >> 3, c8 = (chunk & 7) * 8;
            *(int4*)&As[row][c8] = *(const int4*)&A[(size_t)(bm + row) * K + k0 + c8];
            *(int4*)&Bs[row][c8] = *(const int4*)&Bt[(size_t)(bn + row) * K + k0 + c8];
        }
        __syncthreads();
        #pragma unroll
        for (int kk = 0; kk < 2; ++kk) {
            bf16x8 af[4], bfv[4];
            #pragma unroll
            for (int i = 0; i < 4; i++) af[i] = ld_bf8(&As[wm + i * 16 + l16][kk * 32 + lg * 8]);
            #pragma unroll
            for (int j = 0; j < 4; j++) bfv[j] = ld_bf8(&Bs[wn + j * 16 + l16][kk * 32 + lg * 8]);
            #pragma unroll
            for (int i = 0; i < 4; i++)
                #pragma unroll
                for (int j = 0; j < 4; j++)
                    acc[i][j] = __builtin_amdgcn_mfma_f32_16x16x32_bf16(af[i], bfv[j], acc[i][j], 0, 0, 0);
        }
    }
    #pragma unroll
    for (int i = 0; i < 4; i++)
        #pragma unroll
        for (int j = 0; j < 4; j++) {
            int col = bn + wn + j * 16 + l16;
            #pragma unroll
            for (int r = 0; r < 4; r++) {
                int row = bm + wm + i * 16 + lg * 4 + r;
                float v = acc[i][j][r];
                if (MODE == 0) {
                    Cf[(size_t)row * N + col] = v;
                } else {
                    if (col < 2048) qkb[(size_t)row * 2048 + col] = f2bu(v);
                    else            vtb[(size_t)(col - 2048) * T + row] = f2bu(v);
                }
            }
        }
}

// ---------------- attention ----------------
// grid (T/64, NH); 256 threads = 4 waves, wave wv owns q rows [q0+16*wv, q0+16*wv+16)
__global__ __launch_bounds__(256)
void attn_kernel(const u16* __restrict__ qkb, const u16* __restrict__ vtb,
                 const float* __restrict__ biasT,
                 const int* __restrict__ seqid, const int* __restrict__ kvsA, const int* __restrict__ kveA,
                 u16* __restrict__ attnb, int T) {
    __shared__ __attribute__((aligned(16))) u16 Ks[64][72];   // [key][d]
    __shared__ __attribute__((aligned(16))) u16 Vs[64][72];   // [d][key]
    __shared__ __attribute__((aligned(16))) u16 Ps[4][16][72];
    const int h = blockIdx.y;
    const int q0 = blockIdx.x * 64;
    const int tid = threadIdx.x;
    const int l = tid & 63, wv = tid >> 6;
    const int l16 = l & 15, lg = l >> 4;

    bf16x8 qf[2];
    {
        int tq = q0 + wv * 16 + l16;
        const u16* qp = qkb + (size_t)tq * 2048 + h * 64 + lg * 8;
        qf[0] = ld_bf8(qp);
        qf[1] = ld_bf8(qp + 32);
    }
    int s0 = seqid[q0], s1 = seqid[q0 + 63];
    bool uni = (s0 == s1) && (s0 >= 0);
    int kvA = uni ? kvsA[q0] : 0;
    int kvB = uni ? kveA[q0] : T;

    int tqr[4], sqr[4];
    #pragma unroll
    for (int r = 0; r < 4; r++) { tqr[r] = q0 + wv * 16 + lg * 4 + r; sqr[r] = seqid[tqr[r]]; }
    float m_run[4], l_run[4];
    f32x4 o[4];
    #pragma unroll
    for (int r = 0; r < 4; r++) { m_run[r] = -3e38f; l_run[r] = 0.f; }
    #pragma unroll
    for (int d = 0; d < 4; d++)
        #pragma unroll
        for (int r = 0; r < 4; r++) o[d][r] = 0.f;

    const int Wb = 2 * T - 1;
    for (int base = kvA; base < kvB; base += 64) {
        __syncthreads();
        #pragma unroll
        for (int c = 0; c < 2; ++c) {
            int chunk = c * 256 + tid;
            int row = chunk >> 3, c8 = (chunk & 7) * 8;
            int tk = base + row;
            int4 kv4; kv4.x = kv4.y = kv4.z = kv4.w = 0;
            if (tk < T) kv4 = *(const int4*)&qkb[(size_t)tk * 2048 + 1024 + h * 64 + c8];
            *(int4*)&Ks[row][c8] = kv4;
            int kb = base + c8;
            int4 vv4; vv4.x = vv4.y = vv4.z = vv4.w = 0;
            if (kb + 8 <= T) vv4 = *(const int4*)&vtb[(size_t)(h * 64 + row) * T + kb];
            *(int4*)&Vs[row][c8] = vv4;
        }
        __syncthreads();

        f32x4 s[4];
        #pragma unroll
        for (int kt = 0; kt < 4; kt++)
            #pragma unroll
            for (int r = 0; r < 4; r++) s[kt][r] = 0.f;
        #pragma unroll
        for (int kk = 0; kk < 2; kk++)
            #pragma unroll
            for (int kt = 0; kt < 4; kt++) {
                bf16x8 kf = ld_bf8(&Ks[kt * 16 + l16][kk * 32 + lg * 8]);
                s[kt] = __builtin_amdgcn_mfma_f32_16x16x32_bf16(qf[kk], kf, s[kt], 0, 0, 0);
            }

        #pragma unroll
        for (int r = 0; r < 4; r++) {
            int tq = tqr[r], sq = sqr[r];
            float vs[4];
            float rowmax = -3e38f;
            #pragma unroll
            for (int kt = 0; kt < 4; kt++) {
                int tk = base + kt * 16 + l16;
                float v = s[kt][r];
                if (sq < 0) {
                    v = 0.f;   // invalid query row -> uniform weights (matches reference)
                } else {
                    int tkc = tk < T ? tk : T - 1;
                    bool ok = (tk < kvB) && (seqid[tkc] == sq);
                    if (ok) v += biasT[(size_t)h * Wb + (tk - tq) + (T - 1)];
                    else    v = -3e38f;
                }
                vs[kt] = v;
                rowmax = fmaxf(rowmax, v);
            }
            #pragma unroll
            for (int m = 1; m < 16; m <<= 1) rowmax = fmaxf(rowmax, __shfl_xor(rowmax, m, 64));
            float mnew = fmaxf(m_run[r], rowmax);
            float scale = __expf(m_run[r] - mnew);
            float rsum = 0.f;
            #pragma unroll
            for (int kt = 0; kt < 4; kt++) {
                float p = (vs[kt] > -1e37f) ? __expf(vs[kt] - mnew) : 0.f;
                rsum += p;
                Ps[wv][lg * 4 + r][kt * 16 + l16] = f2bu(p);
            }
            #pragma unroll
            for (int m = 1; m < 16; m <<= 1) rsum += __shfl_xor(rsum, m, 64);
            l_run[r] = l_run[r] * scale + rsum;
            m_run[r] = mnew;
            #pragma unroll
            for (int d = 0; d < 4; d++) o[d][r] *= scale;
        }
        __syncthreads();

        bf16x8 pf[2];
        pf[0] = ld_bf8(&Ps[wv][l16][lg * 8]);
        pf[1] = ld_bf8(&Ps[wv][l16][32 + lg * 8]);
        #pragma unroll
        for (int dt = 0; dt < 4; dt++)
            #pragma unroll
            for (int kk = 0; kk < 2; kk++) {
                bf16x8 vf = ld_bf8(&Vs[dt * 16 + l16][kk * 32 + lg * 8]);
                o[dt] = __builtin_amdgcn_mfma_f32_16x16x32_bf16(pf[kk], vf, o[dt], 0, 0, 0);
            }
    }

    #pragma unroll
    for (int dt = 0; dt < 4; dt++)
        #pragma unroll
        for (int r = 0; r < 4; r++) {
            float val = o[dt][r] / l_run[r];
            attnb[(size_t)tqr[r] * 1024 + h * 64 + dt * 16 + l16] = f2bu(val);
        }
}

// ---------------- launch ----------------
extern "C" void kernel_launch(void* const* d_in, const int* in_sizes, int n_in,
                              void* d_out, int out_size, void* d_ws, size_t ws_size,
                              hipStream_t stream) {
    const float* x   = (const float*)d_in[0];
    const float* Wq  = (const float*)d_in[1];
    const float* Wk  = (const float*)d_in[2];
    const float* Wv  = (const float*)d_in[3];
    const float* Wo  = (const float*)d_in[4];
    const float* tbl = (const float*)d_in[5];
    const int* q_lens = (const int*)d_in[6];
    const int T = in_sizes[0] / 1024;
    const int nseq = in_sizes[6];

    char* ws = (char*)d_ws;
    auto alloc = [&](size_t bytes) { char* p = ws; ws += (bytes + 255) & ~(size_t)255; return p; };
    u16*   xb    = (u16*)alloc((size_t)T * 1024 * 2);
    u16*   Wt    = (u16*)alloc((size_t)3072 * 1024 * 2);
    u16*   Wot   = (u16*)alloc((size_t)1024 * 1024 * 2);
    u16*   qkb   = (u16*)alloc((size_t)T * 2048 * 2);
    u16*   vtb   = (u16*)alloc((size_t)1024 * T * 2);
    u16*   attnb = (u16*)alloc((size_t)T * 1024 * 2);
    float* biasT = (float*)alloc((size_t)NH * (2 * T - 1) * 4);
    int*   seqid = (int*)alloc((size_t)T * 4);
    int*   kvs   = (int*)alloc((size_t)T * 4);
    int*   kve   = (int*)alloc((size_t)T * 4);

    prep_cast<<<dim3((T * 1024 / 4 + 255) / 256), dim3(256), 0, stream>>>(x, xb, T * 1024);
    prep_transpose<<<dim3(32, 32), dim3(32, 8), 0, stream>>>(Wq, Wt);
    prep_transpose<<<dim3(32, 32), dim3(32, 8), 0, stream>>>(Wk, Wt + (size_t)1024 * 1024);
    prep_transpose<<<dim3(32, 32), dim3(32, 8), 0, stream>>>(Wv, Wt + (size_t)2048 * 1024);
    prep_transpose<<<dim3(32, 32), dim3(32, 8), 0, stream>>>(Wo, Wot);
    prep_bias<<<dim3((NH * (2 * T - 1) + 255) / 256), dim3(256), 0, stream>>>(tbl, biasT, T);
    prep_meta<<<dim3((T + 255) / 256), dim3(256), 0, stream>>>(q_lens, nseq, T, seqid, kvs, kve);

    gemm_bt<1><<<dim3(T / 128, 3072 / 128), dim3(256), 0, stream>>>(
        xb, Wt, T, 3072, 1024, T, nullptr, qkb, vtb);
    attn_kernel<<<dim3(T / 64, NH), dim3(256), 0, stream>>>(
        qkb, vtb, biasT, seqid, kvs, kve, attnb, T);
    gemm_bt<0><<<dim3(T / 128, 1024 / 128), dim3(256), 0, stream>>>(
        attnb, Wot, T, 1024, 1024, T, (float*)d_out, nullptr, nullptr);
}

// Round 2
// 159.728 us; speedup vs baseline: 1.2266x; 1.2266x over previous
//
#include <hip/hip_runtime.h>

#define NH 16

typedef __bf16 bf16x8 __attribute__((ext_vector_type(8)));
typedef unsigned short u16x8 __attribute__((ext_vector_type(8)));
typedef float f32x4 __attribute__((ext_vector_type(4)));
typedef unsigned short u16;
typedef unsigned int u32;

__device__ __forceinline__ u16 f2bu(float f) {
    unsigned int u = __builtin_bit_cast(unsigned int, f);
    u = (u + 0x7FFFu + ((u >> 16) & 1u)) >> 16;
    return (u16)u;
}
__device__ __forceinline__ bf16x8 ld_bf8(const u16* p) {
    return __builtin_bit_cast(bf16x8, *(const u16x8*)p);
}
// async global->LDS, 16B per lane; LDS dest = base + lane*16 (wave-linear)
__device__ __forceinline__ void gl_lds16(const void* g, void* l) {
    __builtin_amdgcn_global_load_lds((const __attribute__((address_space(1))) void*)g,
                                     (__attribute__((address_space(3))) void*)l, 16, 0, 0);
}

// ---------------- prep kernels ----------------
__global__ void prep_cast(const float* __restrict__ x, u16* __restrict__ xb, int n) {
    int i = (blockIdx.x * 256 + threadIdx.x) * 4;
    if (i >= n) return;
    float4 v = *(const float4*)&x[i];
    u16 o0 = f2bu(v.x), o1 = f2bu(v.y), o2 = f2bu(v.z), o3 = f2bu(v.w);
    xb[i] = o0; xb[i+1] = o1; xb[i+2] = o2; xb[i+3] = o3;
}

__global__ void prep_transpose(const float* __restrict__ src, u16* __restrict__ dst) {
    __shared__ float tile[32][33];
    int r0 = blockIdx.y * 32, c0 = blockIdx.x * 32;
    int tx = threadIdx.x, ty = threadIdx.y;
    #pragma unroll
    for (int i = 0; i < 32; i += 8)
        tile[ty + i][tx] = src[(size_t)(r0 + ty + i) * 1024 + c0 + tx];
    __syncthreads();
    #pragma unroll
    for (int i = 0; i < 32; i += 8)
        dst[(size_t)(c0 + ty + i) * 1024 + r0 + tx] = f2bu(tile[tx][ty + i]);
}

__device__ __forceinline__ int rel_bucket(int delta) {
    int n = -delta;
    int ret = (n < 0) ? 16 : 0;
    int na = n < 0 ? -n : n;
    int b;
    if (na < 8) b = na;
    else if (na < 12) b = 8;
    else if (na < 16) b = 9;
    else if (na < 23) b = 10;
    else if (na < 32) b = 11;
    else if (na < 46) b = 12;
    else if (na < 64) b = 13;
    else if (na < 91) b = 14;
    else b = 15;
    return b + ret;
}

__global__ void prep_bias(const float* __restrict__ tbl, float* __restrict__ biasT, int T) {
    int idx = blockIdx.x * 256 + threadIdx.x;
    int W = 2 * T - 1;
    if (idx >= NH * W) return;
    int d = idx % W - (T - 1);
    int h = idx / W;
    biasT[idx] = tbl[rel_bucket(d) * NH + h];
}

__global__ void prep_meta(const int* __restrict__ q_lens, int nseq, int T,
                          int* __restrict__ seqid, int* __restrict__ kvs, int* __restrict__ kve) {
    int t = blockIdx.x * 256 + threadIdx.x;
    if (t >= T) return;
    int start = 0, sid = -1, a = 0, b = 0;
    for (int i = 0; i < nseq; ++i) {
        int len = q_lens[i];
        if (t >= start && t < start + len) { sid = i; a = start; b = start + len; }
        start += len;
    }
    seqid[t] = sid; kvs[t] = a; kve[t] = b;
}

// ---------------- GEMM ----------------
// A [M][K] bf16, Bt [N][K] bf16. BK=64 steps, global_load_lds staging with
// XOR-swizzled source slots; reads apply the same swizzle -> <=2-way conflicts.
// MODE 0: C f32 [M][N].  MODE 1: qkv epilogue (cols<2048 -> qkb, cols>=2048 -> vtb
// transposed via LDS for coalesced stores).
template<int MODE, int BM>
__global__ __launch_bounds__(256)
void gemm_bt(const u16* __restrict__ A, const u16* __restrict__ Bt,
             int N, int K, int T,
             float* __restrict__ Cf, u16* __restrict__ qkb, u16* __restrict__ vtb) {
    constexpr int MI = BM / 32;                  // A-frags per wave
    constexpr int LDSN = (MODE == 1) ? 128 * 136 : (BM * 64 + 128 * 64);
    __shared__ __attribute__((aligned(16))) u16 lds[LDSN];
    u16* As = lds;                               // [BM][64] linear, swizzled slots
    u16* Bs = lds + BM * 64;                     // [128][64]
    const int tid = threadIdx.x;
    const int l = tid & 63, wv = tid >> 6;
    const int l16 = l & 15, lg = l >> 4;
    const int wm = (wv >> 1) * (BM / 2), wn = (wv & 1) * 64;
    const int bm = blockIdx.x * BM, bn = blockIdx.y * 128;
    const int lrow = l >> 3, lslot = l & 7;      // staging: row-within-chunk, slot
    f32x4 acc[MI][4];
    #pragma unroll
    for (int i = 0; i < MI; i++)
        #pragma unroll
        for (int j = 0; j < 4; j++)
            #pragma unroll
            for (int r = 0; r < 4; r++) acc[i][j][r] = 0.f;

    for (int k0 = 0; k0 < K; k0 += 64) {
        __syncthreads();
        #pragma unroll
        for (int c = 0; c < MI; ++c) {           // A: BM/8 chunks of 8 rows
            int chunk = c * 4 + wv;
            int row = chunk * 8 + lrow;
            int gslot = lslot ^ (row & 7);
            gl_lds16(&A[(size_t)(bm + row) * K + k0 + gslot * 8], &As[chunk * 512]);
        }
        #pragma unroll
        for (int c = 0; c < 4; ++c) {            // B: 16 chunks of 8 rows
            int chunk = c * 4 + wv;
            int row = chunk * 8 + lrow;
            int gslot = lslot ^ (row & 7);
            gl_lds16(&Bt[(size_t)(bn + row) * K + k0 + gslot * 8], &Bs[chunk * 512]);
        }
        __syncthreads();
        #pragma unroll
        for (int kk = 0; kk < 2; ++kk) {
            bf16x8 af[MI], bfv[4];
            #pragma unroll
            for (int i = 0; i < MI; i++) {
                int row = wm + i * 16 + l16;
                af[i] = ld_bf8(&As[row * 64 + (((kk * 4 + lg) ^ (row & 7)) * 8)]);
            }
            #pragma unroll
            for (int j = 0; j < 4; j++) {
                int row = wn + j * 16 + l16;
                bfv[j] = ld_bf8(&Bs[row * 64 + (((kk * 4 + lg) ^ (row & 7)) * 8)]);
            }
            #pragma unroll
            for (int i = 0; i < MI; i++)
                #pragma unroll
                for (int j = 0; j < 4; j++)
                    acc[i][j] = __builtin_amdgcn_mfma_f32_16x16x32_bf16(af[i], bfv[j], acc[i][j], 0, 0, 0);
        }
    }

    if (MODE == 0) {
        #pragma unroll
        for (int i = 0; i < MI; i++)
            #pragma unroll
            for (int j = 0; j < 4; j++) {
                int col = bn + wn + j * 16 + l16;
                #pragma unroll
                for (int r = 0; r < 4; r++) {
                    int row = bm + wm + i * 16 + lg * 4 + r;
                    Cf[(size_t)row * N + col] = acc[i][j][r];
                }
            }
    } else if (bn < 2048) {
        #pragma unroll
        for (int i = 0; i < MI; i++)
            #pragma unroll
            for (int j = 0; j < 4; j++) {
                int col = bn + wn + j * 16 + l16;
                #pragma unroll
                for (int r = 0; r < 4; r++) {
                    int row = bm + wm + i * 16 + lg * 4 + r;
                    qkb[(size_t)row * 2048 + col] = f2bu(acc[i][j][r]);
                }
            }
    } else {
        // transpose 128x128 tile through LDS -> coalesced vtb stores
        __syncthreads();
        #pragma unroll
        for (int i = 0; i < MI; i++)
            #pragma unroll
            for (int j = 0; j < 4; j++) {
                int cl = wn + j * 16 + l16;
                #pragma unroll
                for (int r = 0; r < 4; r++)
                    lds[cl * 136 + wm + i * 16 + lg * 4 + r] = f2bu(acc[i][j][r]);
            }
        __syncthreads();
        int cl = tid >> 1, hf = tid & 1;
        size_t gb = (size_t)(bn - 2048 + cl) * T + bm + hf * 64;
        #pragma unroll
        for (int k2 = 0; k2 < 8; ++k2) {
            int4 v4 = *(const int4*)&lds[cl * 136 + hf * 64 + k2 * 8];
            *(int4*)&vtb[gb + k2 * 8] = v4;
        }
    }
}

// ---------------- attention ----------------
// grid (T/64, NH); 4 waves, wave wv owns q rows [q0+16*wv, +16).
// Deferred max (m=0) + deferred denominator; bias staged in LDS per block.
__global__ __launch_bounds__(256)
void attn_kernel(const u16* __restrict__ qkb, const u16* __restrict__ vtb,
                 const float* __restrict__ biasT,
                 const int* __restrict__ seqid, const int* __restrict__ kvsA,
                 const int* __restrict__ kveA,
                 u16* __restrict__ attnb, int T) {
    __shared__ __attribute__((aligned(16))) u16 Ks[64][72];   // [key][d]
    __shared__ __attribute__((aligned(16))) u16 Vs[64][72];   // [d][key]
    __shared__ __attribute__((aligned(16))) u16 Ps[4][16][72];
    __shared__ float biasLds[2304];
    const int h = blockIdx.y;
    const int q0 = blockIdx.x * 64;
    const int tid = threadIdx.x;
    const int l = tid & 63, wv = tid >> 6;
    const int l16 = l & 15, lg = l >> 4;
    const int Wb = 2 * T - 1;

    bf16x8 qf[2];
    {
        int tq = q0 + wv * 16 + l16;
        const u16* qp = qkb + (size_t)tq * 2048 + h * 64 + lg * 8;
        qf[0] = ld_bf8(qp); qf[1] = ld_bf8(qp + 32);
    }
    const int s0 = seqid[q0], s1 = seqid[q0 + 63];
    const bool uni = (s0 == s1) && (s0 >= 0);
    const int kvA = uni ? kvsA[q0] : 0;
    const int kvB = uni ? kveA[q0] : T;
    const int len = kvB - kvA;

    for (int t = tid; t < len + 126; t += 256) {
        int dlt = kvA - q0 + t - 63;
        dlt = dlt < -(T - 1) ? -(T - 1) : (dlt > T - 1 ? T - 1 : dlt);
        biasLds[t] = biasT[(size_t)h * Wb + dlt + (T - 1)];
    }

    int tqr[4], sqr[4];
    #pragma unroll
    for (int r = 0; r < 4; r++) {
        tqr[r] = q0 + wv * 16 + lg * 4 + r;
        sqr[r] = uni ? s0 : seqid[tqr[r]];
    }
    float psum[4] = {0.f, 0.f, 0.f, 0.f};
    f32x4 o[4];
    #pragma unroll
    for (int d = 0; d < 4; d++)
        #pragma unroll
        for (int r = 0; r < 4; r++) o[d][r] = 0.f;

    for (int base = kvA; base < kvB; base += 64) {
        __syncthreads();
        #pragma unroll
        for (int c = 0; c < 2; ++c) {
            int chunk = c * 256 + tid;
            int row = chunk >> 3, c8 = (chunk & 7) * 8;
            int tk = base + row;
            int4 kv4; kv4.x = kv4.y = kv4.z = kv4.w = 0;
            if (tk < T) kv4 = *(const int4*)&qkb[(size_t)tk * 2048 + 1024 + h * 64 + c8];
            *(int4*)&Ks[row][c8] = kv4;
            int4 vv4; vv4.x = vv4.y = vv4.z = vv4.w = 0;
            if (base + c8 + 8 <= T) vv4 = *(const int4*)&vtb[(size_t)(h * 64 + row) * T + base + c8];
            *(int4*)&Vs[row][c8] = vv4;
        }
        __syncthreads();

        f32x4 s[4];
        #pragma unroll
        for (int kt = 0; kt < 4; kt++)
            #pragma unroll
            for (int r = 0; r < 4; r++) s[kt][r] = 0.f;
        #pragma unroll
        for (int kk = 0; kk < 2; kk++)
            #pragma unroll
            for (int kt = 0; kt < 4; kt++) {
                bf16x8 kf = ld_bf8(&Ks[kt * 16 + l16][kk * 32 + lg * 8]);
                s[kt] = __builtin_amdgcn_mfma_f32_16x16x32_bf16(qf[kk], kf, s[kt], 0, 0, 0);
            }

        const bool fullT = (base + 64 <= kvB);
        const int cb = (base - kvA) + 63 + l16 - wv * 16 - lg * 4;
        #pragma unroll
        for (int r = 0; r < 4; r++) {
            const float* bp = &biasLds[cb - r];
            #pragma unroll
            for (int kt = 0; kt < 4; kt++) {
                float p = __expf(s[kt][r] + bp[kt * 16]);
                if (uni) {
                    if (!fullT && base + kt * 16 + l16 >= kvB) p = 0.f;
                } else {
                    int tk = base + kt * 16 + l16;
                    int tkc = tk < T ? tk : T - 1;
                    bool ok = (tk < T) && (seqid[tkc] == sqr[r]);
                    p = (sqr[r] < 0) ? 1.f : (ok ? p : 0.f);
                }
                psum[r] += p;
                Ps[wv][lg * 4 + r][kt * 16 + l16] = f2bu(p);
            }
        }
        // PV — same-wave LDS RAW, no barrier needed
        bf16x8 pf0 = ld_bf8(&Ps[wv][l16][lg * 8]);
        bf16x8 pf1 = ld_bf8(&Ps[wv][l16][32 + lg * 8]);
        #pragma unroll
        for (int dt = 0; dt < 4; dt++) {
            bf16x8 vf0 = ld_bf8(&Vs[dt * 16 + l16][lg * 8]);
            bf16x8 vf1 = ld_bf8(&Vs[dt * 16 + l16][32 + lg * 8]);
            o[dt] = __builtin_amdgcn_mfma_f32_16x16x32_bf16(pf0, vf0, o[dt], 0, 0, 0);
            o[dt] = __builtin_amdgcn_mfma_f32_16x16x32_bf16(pf1, vf1, o[dt], 0, 0, 0);
        }
    }

    float lsum[4];
    #pragma unroll
    for (int r = 0; r < 4; r++) {
        float v = psum[r];
        #pragma unroll
        for (int m = 1; m < 16; m <<= 1) v += __shfl_xor(v, m, 64);
        lsum[r] = v;
    }
    #pragma unroll
    for (int dt = 0; dt < 4; dt++)
        #pragma unroll
        for (int r = 0; r < 4; r++)
            attnb[(size_t)tqr[r] * 1024 + h * 64 + dt * 16 + l16] = f2bu(o[dt][r] / lsum[r]);
}

// ---------------- launch ----------------
extern "C" void kernel_launch(void* const* d_in, const int* in_sizes, int n_in,
                              void* d_out, int out_size, void* d_ws, size_t ws_size,
                              hipStream_t stream) {
    const float* x   = (const float*)d_in[0];
    const float* Wq  = (const float*)d_in[1];
    const float* Wk  = (const float*)d_in[2];
    const float* Wv  = (const float*)d_in[3];
    const float* Wo  = (const float*)d_in[4];
    const float* tbl = (const float*)d_in[5];
    const int* q_lens = (const int*)d_in[6];
    const int T = in_sizes[0] / 1024;
    const int nseq = in_sizes[6];

    char* ws = (char*)d_ws;
    auto alloc = [&](size_t bytes) { char* p = ws; ws += (bytes + 255) & ~(size_t)255; return p; };
    u16*   xb    = (u16*)alloc((size_t)T * 1024 * 2);
    u16*   Wt    = (u16*)alloc((size_t)3072 * 1024 * 2);
    u16*   Wot   = (u16*)alloc((size_t)1024 * 1024 * 2);
    u16*   qkb   = (u16*)alloc((size_t)T * 2048 * 2);
    u16*   vtb   = (u16*)alloc((size_t)1024 * T * 2);
    u16*   attnb = (u16*)alloc((size_t)T * 1024 * 2);
    float* biasT = (float*)alloc((size_t)NH * (2 * T - 1) * 4);
    int*   seqid = (int*)alloc((size_t)T * 4);
    int*   kvs   = (int*)alloc((size_t)T * 4);
    int*   kve   = (int*)alloc((size_t)T * 4);

    prep_cast<<<dim3((T * 1024 / 4 + 255) / 256), dim3(256), 0, stream>>>(x, xb, T * 1024);
    prep_transpose<<<dim3(32, 32), dim3(32, 8), 0, stream>>>(Wq, Wt);
    prep_transpose<<<dim3(32, 32), dim3(32, 8), 0, stream>>>(Wk, Wt + (size_t)1024 * 1024);
    prep_transpose<<<dim3(32, 32), dim3(32, 8), 0, stream>>>(Wv, Wt + (size_t)2048 * 1024);
    prep_transpose<<<dim3(32, 32), dim3(32, 8), 0, stream>>>(Wo, Wot);
    prep_bias<<<dim3((NH * (2 * T - 1) + 255) / 256), dim3(256), 0, stream>>>(tbl, biasT, T);
    prep_meta<<<dim3((T + 255) / 256), dim3(256), 0, stream>>>(q_lens, nseq, T, seqid, kvs, kve);

    gemm_bt<1, 128><<<dim3(T / 128, 3072 / 128), dim3(256), 0, stream>>>(
        xb, Wt, 3072, 1024, T, nullptr, qkb, vtb);
    attn_kernel<<<dim3(T / 64, NH), dim3(256), 0, stream>>>(
        qkb, vtb, biasT, seqid, kvs, kve, attnb, T);
    gemm_bt<0, 64><<<dim3(T / 64, 1024 / 128), dim3(256), 0, stream>>>(
        attnb, Wot, 1024, 1024, T, (float*)d_out, nullptr, nullptr);
}